// Round 8
// baseline (109.440 us; speedup 1.0000x reference)
//
#include <hip/hip_runtime.h>

// Problem constants
#define NVEC 65536      // B*R*C = 8*16*512
#define KDIM 64
#define SDIM 512

// Output layout (flat float32)
#define Z_OFF       4194304     // NVEC*KDIM
#define LCOMMIT_OFF 4259840
#define LCODE_OFF   4259841
#define E_OFF       4259842

typedef _Float16 half8    __attribute__((ext_vector_type(8)));
typedef float    floatx16 __attribute__((ext_vector_type(16)));

// ws: c32 [SDIM*KDIM] f32, cnorm [SDIM] f32, cbf16 [SDIM*KDIM*2] f16
// cbf16 chunk layout (R4-verified): half index
//   (s>>5)*4096 + p*2048 + q*512 + h*256 + (s&31)*8 + j
// R8: B-fragments are read DIRECTLY from global (L2-hot 128 KB codebook) with
// per-lane addresses — no LDS staging, no DMA, no barriers in the K-loop.

__global__ void vq_prep(const float* __restrict__ c_sum,
                        const float* __restrict__ c_count,
                        float* __restrict__ c32,
                        float* __restrict__ cnorm,
                        _Float16* __restrict__ cbf16,
                        float* __restrict__ out) {
    int s = blockIdx.x;          // 0..511
    int k = threadIdx.x;         // 0..63
    float cnt = c_count[s];
    float inv = 1.0f / fmaxf(cnt, 0.01f);
    float x = c_sum[s * KDIM + k] * inv;
    c32[s * KDIM + k] = x;
    float sq = x * x;
    #pragma unroll
    for (int off = 32; off > 0; off >>= 1)
        sq += __shfl_down(sq, off);
    if (k == 0) cnorm[s] = sq;

    __shared__ _Float16 hb[64], lb[64];
    _Float16 hi = (_Float16)x;
    float hiF = (float)hi;
    _Float16 lo = (_Float16)(x - hiF);
    hb[k] = hi; lb[k] = lo;
    __syncthreads();
    if (k < 16) {
        int p  = k >> 3;
        int qh = k & 7;                       // q*2 + h
        int k0 = (qh >> 1) * 16 + (qh & 1) * 8;
        const _Float16* srcb = (p ? lb : hb) + k0;
        half8 v;
        #pragma unroll
        for (int j = 0; j < 8; ++j) v[j] = srcb[j];
        size_t chunk = ((size_t)(s >> 5) * 16 + p * 8 + qh) * 32 + (s & 31);
        *(half8*)(cbf16 + chunk * 8) = v;
    }
    if (s == 0 && k == 0) {
        out[LCOMMIT_OFF] = 0.0f;
        out[LCODE_OFF]   = 0.0f;
    }
}

// 512 blocks x 256 threads (4 waves, M=32/wave). Barrier-free K-loop:
// B-fragments stream global->VGPR (L2-hot), MFMA interleaved by the scheduler.
__global__ __launch_bounds__(256, 2) void vq_main(const float* __restrict__ vecs,
                                                  const _Float16* __restrict__ cbf16,
                                                  const float* __restrict__ c32,
                                                  const float* __restrict__ cnorm,
                                                  float* __restrict__ out) {
    __shared__ float cnL[512];
    __shared__ float vnL[4][32];
    __shared__ int   zL[4][32];
    __shared__ float esumL[8];

    const int tx   = threadIdx.x;
    const int lane = tx & 63;
    const int w    = tx >> 6;
    const int col  = lane & 31;
    const int h    = lane >> 5;
    const int wvec = (int)blockIdx.x * 128 + w * 32;

    // whole cnorm into LDS once (2 KB); only barrier before the K-loop
    cnL[tx]       = cnorm[tx];
    cnL[tx + 256] = cnorm[tx + 256];

    // ---- A fragments (hi/lo f16) + vnorm (R4..R7-verified tree) ----
    half8 ahi[4], alo[4];
    float vnp = 0.0f;
    const float* arow = vecs + (size_t)(wvec + col) * KDIM + h * 8;
    #pragma unroll
    for (int q = 0; q < 4; ++q) {
        float4 x0 = *(const float4*)(arow + q * 16);
        float4 x1 = *(const float4*)(arow + q * 16 + 4);
        #define CVT(X, J) { float xx = (X); _Float16 hi5 = (_Float16)xx; \
                            float hf = (float)hi5; ahi[q][J] = hi5; \
                            alo[q][J] = (_Float16)(xx - hf); vnp += xx * xx; }
        CVT(x0.x, 0) CVT(x0.y, 1) CVT(x0.z, 2) CVT(x0.w, 3)
        CVT(x1.x, 4) CVT(x1.y, 5) CVT(x1.z, 6) CVT(x1.w, 7)
        #undef CVT
    }
    vnp += __shfl_xor(vnp, 32);
    if (h == 0) vnL[w][col] = vnp;

    __syncthreads();   // cnL visible to all waves

    // running argmax of m = -cn/2 + dot (== argmin dist; first-index ties)
    float bm[16];
    int   bi[16];
    #pragma unroll
    for (int r = 0; r < 16; ++r) { bm[r] = -3.4e38f; bi[r] = 0; }

    for (int t = 0; t < 4; ++t) {
        // per-lane global B pointer for this tile (R4 layout, L2-resident)
        const _Float16* bt = cbf16 + (size_t)t * 16384 + lane * 8;
        #pragma unroll
        for (int sub = 0; sub < 4; ++sub) {
            const _Float16* bb = bt + sub * 4096;
            float ci = -0.5f * cnL[t * 128 + sub * 32 + col];
            floatx16 a0, a1;
            #pragma unroll
            for (int r = 0; r < 16; ++r) { a0[r] = ci; a1[r] = 0.0f; }
            #pragma unroll
            for (int q = 0; q < 4; ++q) {
                half8 bh = *(const half8*)(bb + q * 512);           // global, L2-hot
                half8 bl = *(const half8*)(bb + 2048 + q * 512);
                a0 = __builtin_amdgcn_mfma_f32_32x32x16_f16(ahi[q], bh, a0, 0, 0, 0);
                a1 = __builtin_amdgcn_mfma_f32_32x32x16_f16(alo[q], bh, a1, 0, 0, 0);
                a1 = __builtin_amdgcn_mfma_f32_32x32x16_f16(ahi[q], bl, a1, 0, 0, 0);
            }
            int n = t * 128 + sub * 32 + col;
            #pragma unroll
            for (int r = 0; r < 16; ++r) {
                float m = a0[r] + a1[r];
                if (m > bm[r]) { bm[r] = m; bi[r] = n; }   // strict >, increasing n
            }
        }
    }

    // ---- cross-lane argmax per row (32 cols; xor<=16 stays within h) ----
    #pragma unroll
    for (int r = 0; r < 16; ++r) {
        float v = bm[r]; int i = bi[r];
        #pragma unroll
        for (int off = 16; off > 0; off >>= 1) {
            float ov = __shfl_xor(v, off);
            int   oi = __shfl_xor(i, off);
            if (ov > v || (ov == v && oi < i)) { v = ov; i = oi; }
        }
        bm[r] = v; bi[r] = i;
    }

    if (col == 0) {
        float esum = 0.0f;
        #pragma unroll
        for (int r = 0; r < 16; ++r) {
            int row = (r & 3) + 8 * (r >> 2) + 4 * h;   // C/D row map (verified)
            int vid = wvec + row;
            float err = fmaxf(vnL[w][row] - 2.0f * bm[r], 0.0f);
            out[Z_OFF + vid] = (float)bi[r];
            out[E_OFF + vid] = err;
            zL[w][row] = bi[r];
            esum += err;
        }
        esumL[w * 2 + h] = esum;
    }

    // ---- vecs_hat gather from c32 (L2-hot), coalesced float4 stores ----
    #pragma unroll
    for (int it = 0; it < 8; ++it) {
        int row = it * 4 + (lane >> 4);
        int c4  = lane & 15;
        int z   = zL[w][row];
        float4 val = *(const float4*)(c32 + (size_t)z * KDIM + c4 * 4);
        *(float4*)(out + (size_t)(wvec + row) * KDIM + c4 * 4) = val;
    }

    // ---- ONE same-address atomic per block (R7 fix, kept) ----
    __syncthreads();
    if (tx == 0) {
        float tot = esumL[0] + esumL[1] + esumL[2] + esumL[3]
                  + esumL[4] + esumL[5] + esumL[6] + esumL[7];
        atomicAdd(out + LCOMMIT_OFF, tot * (1.0f / (float)NVEC));
    }
}

extern "C" void kernel_launch(void* const* d_in, const int* in_sizes, int n_in,
                              void* d_out, int out_size, void* d_ws, size_t ws_size,
                              hipStream_t stream) {
    const float* vecs    = (const float*)d_in[0];  // [8,16,512,64]
    const float* c_sum   = (const float*)d_in[1];  // [512,64]
    const float* c_count = (const float*)d_in[2];  // [512]
    float* out = (float*)d_out;

    float*    c32   = (float*)d_ws;                      // 128 KB
    float*    cnorm = c32 + SDIM * KDIM;                 // 2 KB
    _Float16* cbf16 = (_Float16*)(cnorm + SDIM);         // 128 KB

    vq_prep<<<SDIM, KDIM, 0, stream>>>(c_sum, c_count, c32, cnorm, cbf16, out);
    vq_main<<<NVEC / 128, 256, 0, stream>>>(vecs, cbf16, c32, cnorm, out);
}